// Round 1
// baseline (115.735 us; speedup 1.0000x reference)
//
#include <hip/hip_runtime.h>

// SinkhornAttention: b=4,h=8,t=8192,dh=64, BUCKETS=64, bucket size 128.
// Stage 1: bucket sums -> x[bh][64][128]
// Stage 2: R=softmax(relu(x@W)); top-1 -> (v_u, r_u) per (bh,u)
// Stage 3: per-bucket attention with K_cat=[r_u*K[v_u];K[u]], V_cat likewise.

#define T_TOK 8192
#define SCALE 0.04419417382415922f  // 512^-0.5

typedef __attribute__((ext_vector_type(4))) float f32x4;
typedef __attribute__((ext_vector_type(8))) short bf16x8;

__device__ __forceinline__ unsigned short f2bf(float f) {
  union { float f; unsigned u; } v; v.f = f;
  unsigned r = v.u + 0x7FFFu + ((v.u >> 16) & 1u);  // RNE
  return (unsigned short)(r >> 16);
}
__device__ __forceinline__ unsigned pack2(float a, float b) {
  return (unsigned)f2bf(a) | ((unsigned)f2bf(b) << 16);
}

// ---------------- Kernel 1: bucket summaries ----------------
// grid 2048 (bh*64), block 128. tid<64: q-dim sums; tid>=64: k-dim sums.
__global__ __launch_bounds__(128) void k1_sums(const float* __restrict__ q,
                                               const float* __restrict__ k,
                                               float* __restrict__ x) {
  int G = blockIdx.x;
  int bhi = G >> 6, u = G & 63;
  int tid = threadIdx.x;
  const float* src = (tid < 64) ? q : k;
  int d = tid & 63;
  const float* p = src + ((size_t)bhi * T_TOK + (size_t)u * 128) * 64 + d;
  float s = 0.f;
  #pragma unroll 8
  for (int t = 0; t < 128; ++t) s += p[(size_t)t * 64];
  x[(size_t)G * 128 + tid] = s;
}

// ---------------- Kernel 2: SortNet top-1 ----------------
// grid 32 (bh), block 64 (one thread per bucket-row u).
__global__ __launch_bounds__(64) void k2_sort(const float* __restrict__ x,
                                              const float* __restrict__ W,
                                              int* __restrict__ ridx,
                                              float* __restrict__ rval) {
  __shared__ float xs[64][132];   // padded: 8-way instead of 64-way conflicts
  __shared__ float Ws[128][64];
  int bhi = blockIdx.x;
  int u = threadIdx.x;
  int hh = bhi & 7;  // bh = b*8 + h
  for (int i = u; i < 64 * 128; i += 64) xs[i >> 7][i & 127] = x[(size_t)bhi * 8192 + i];
  for (int i = u; i < 128 * 64; i += 64) Ws[i >> 6][i & 63] = W[(size_t)hh * 8192 + i];
  __syncthreads();

  float acc[64];
  #pragma unroll
  for (int i = 0; i < 64; ++i) acc[i] = 0.f;
  for (int kk = 0; kk < 128; ++kk) {
    float xr = xs[u][kk];
    #pragma unroll
    for (int vv = 0; vv < 64; ++vv) acc[vv] = fmaf(xr, Ws[kk][vv], acc[vv]);
  }
  // relu, then argmax (first occurrence, matching jnp.argmax)
  float best = -1.f; int bidx = 0;
  #pragma unroll
  for (int vv = 0; vv < 64; ++vv) {
    float a = fmaxf(acc[vv], 0.f);
    acc[vv] = a;
    if (a > best) { best = a; bidx = vv; }
  }
  float s = 0.f;
  #pragma unroll
  for (int vv = 0; vv < 64; ++vv) s += __expf(acc[vv] - best);
  ridx[bhi * 64 + u] = bidx;
  rval[bhi * 64 + u] = 1.f / s;  // softmax value at the argmax
}

// ---------------- Kernel 3: bucketed attention ----------------
// grid 2048, block 512 (8 waves). Wave w owns Q rows [16w,16w+16).
// LDS: [0,32768) K_cat bf16 [256 rows][64], XOR-swizzled
//      [32768,65536) V^T bf16 [64 rows][256 tokens], XOR-swizzled
//      [65536,81920) per-wave P chunk buffers [16][64] bf16, XOR-swizzled
__global__ __launch_bounds__(512, 4) void k3_attn(
    const float* __restrict__ q, const float* __restrict__ k,
    const float* __restrict__ v, const int* __restrict__ ridx,
    const float* __restrict__ rval, float* __restrict__ out) {
  __shared__ unsigned char smem[81920];

  int L = blockIdx.x;
  int G = ((L & 7) << 8) | (L >> 3);  // XCD-contiguous swizzle (2048 % 8 == 0)
  int bhi = G >> 6, u = G & 63;
  int tid = threadIdx.x;
  int l = tid & 63, w = tid >> 6;

  int vu = ridx[G];
  float ru = rval[G];

  const float* kb = k + (size_t)bhi * (T_TOK * 64);
  const float* vb = v + (size_t)bhi * (T_TOK * 64);

  // ---- stage K_cat (rows 0..127 = bucket vu, 128..255 = bucket u) ----
  #pragma unroll
  for (int it = 0; it < 8; ++it) {
    int ci = tid + it * 512;          // 0..4095
    int row = ci >> 4, c4 = ci & 15;  // 16 float4 per 64-f32 row
    int srow = (row < 128) ? (vu * 128 + row) : (u * 128 + row - 128);
    float4 val = *reinterpret_cast<const float4*>(kb + (size_t)srow * 64 + c4 * 4);
    unsigned lo = pack2(val.x, val.y), hi = pack2(val.z, val.w);
    int addr = row * 128 + ((c4 * 8) ^ ((row & 7) << 4));
    *reinterpret_cast<uint2*>(smem + addr) = make_uint2(lo, hi);
  }
  // ---- stage V^T: vt[d][token], d=0..63, token=0..255 ----
  #pragma unroll
  for (int it = 0; it < 8; ++it) {
    int ci = tid + it * 512;
    int t = ci & 255, c4 = ci >> 8;
    int srow = (t < 128) ? (vu * 128 + t) : (u * 128 + t - 128);
    float4 val = *reinterpret_cast<const float4*>(vb + (size_t)srow * 64 + c4 * 4);
    float v4[4] = {val.x, val.y, val.z, val.w};
    #pragma unroll
    for (int jj = 0; jj < 4; ++jj) {
      int d = c4 * 4 + jj;
      int addr = 32768 + d * 512 + ((2 * t) ^ ((d & 7) << 4));
      *reinterpret_cast<unsigned short*>(smem + addr) = f2bf(v4[jj]);
    }
  }

  // ---- Q A-frags direct from global ----
  int m0 = w * 16;
  const float* qrow = q + ((size_t)bhi * T_TOK + (size_t)u * 128 + m0 + (l & 15)) * 64;
  bf16x8 qf[2];
  #pragma unroll
  for (int ks = 0; ks < 2; ++ks) {
    int c0 = ks * 32 + (l >> 4) * 8;
    float4 a = *reinterpret_cast<const float4*>(qrow + c0);
    float4 b = *reinterpret_cast<const float4*>(qrow + c0 + 4);
    bf16x8 f;
    f[0] = (short)f2bf(a.x); f[1] = (short)f2bf(a.y);
    f[2] = (short)f2bf(a.z); f[3] = (short)f2bf(a.w);
    f[4] = (short)f2bf(b.x); f[5] = (short)f2bf(b.y);
    f[6] = (short)f2bf(b.z); f[7] = (short)f2bf(b.w);
    qf[ks] = f;
  }

  __syncthreads();

  // ---- QK^T: dots[16 rows][256 cols] per wave ----
  f32x4 acc[16];
  #pragma unroll
  for (int nt = 0; nt < 16; ++nt) acc[nt] = (f32x4){0.f, 0.f, 0.f, 0.f};
  #pragma unroll
  for (int nt = 0; nt < 16; ++nt) {
    int r = nt * 16 + (l & 15);
    #pragma unroll
    for (int ks = 0; ks < 2; ++ks) {
      int cb = 2 * (ks * 32 + (l >> 4) * 8);
      int addr = r * 128 + (cb ^ ((r & 7) << 4));
      bf16x8 bf = *reinterpret_cast<const bf16x8*>(smem + addr);
      acc[nt] = __builtin_amdgcn_mfma_f32_16x16x32_bf16(qf[ks], bf, acc[nt], 0, 0, 0);
    }
  }

  // ---- softmax (row-local to lane group of 16) ----
  // logits: cols 0..127 were computed against unscaled K[vu]; fold ru here.
  float rm[4] = {-1e30f, -1e30f, -1e30f, -1e30f};
  #pragma unroll
  for (int nt = 0; nt < 16; ++nt) {
    float mult = (nt < 8) ? (SCALE * ru) : SCALE;
    #pragma unroll
    for (int j = 0; j < 4; ++j) {
      float lg = acc[nt][j] * mult;
      acc[nt][j] = lg;
      rm[j] = fmaxf(rm[j], lg);
    }
  }
  #pragma unroll
  for (int j = 0; j < 4; ++j) {
    #pragma unroll
    for (int m = 1; m < 16; m <<= 1) rm[j] = fmaxf(rm[j], __shfl_xor(rm[j], m, 64));
  }
  float rs[4] = {0.f, 0.f, 0.f, 0.f};
  #pragma unroll
  for (int nt = 0; nt < 16; ++nt) {
    #pragma unroll
    for (int j = 0; j < 4; ++j) {
      float p = __expf(acc[nt][j] - rm[j]);
      rs[j] += p;                       // denominator: un-scaled P
      acc[nt][j] = (nt < 8) ? p * ru : p;  // fold ru (V_cat first half) into P
    }
  }
  #pragma unroll
  for (int j = 0; j < 4; ++j) {
    #pragma unroll
    for (int m = 1; m < 16; m <<= 1) rs[j] += __shfl_xor(rs[j], m, 64);
  }
  float inv[4];
  #pragma unroll
  for (int j = 0; j < 4; ++j) inv[j] = 1.f / rs[j];

  // ---- PV: out[16][64] = P[16][256] @ V_cat[256][64], chunked by 64 k ----
  f32x4 oacc[4];
  #pragma unroll
  for (int n = 0; n < 4; ++n) oacc[n] = (f32x4){0.f, 0.f, 0.f, 0.f};
  int pbase = 65536 + w * 2048;
  #pragma unroll
  for (int ch = 0; ch < 4; ++ch) {
    // write P chunk (D-layout -> LDS), per-wave buffer, in-wave ordering only
    #pragma unroll
    for (int nt2 = 0; nt2 < 4; ++nt2) {
      #pragma unroll
      for (int j = 0; j < 4; ++j) {
        int row = (l >> 4) * 4 + j;
        int col = nt2 * 16 + (l & 15);
        int addr = pbase + row * 128 + ((2 * col) ^ ((row & 7) << 4));
        *reinterpret_cast<unsigned short*>(smem + addr) = f2bf(acc[ch * 4 + nt2][j]);
      }
    }
    #pragma unroll
    for (int ks = 0; ks < 2; ++ks) {
      int prow = l & 15;
      int pcb = 2 * (ks * 32 + (l >> 4) * 8);
      int paddr = pbase + prow * 128 + (pcb ^ ((prow & 7) << 4));
      bf16x8 pf = *reinterpret_cast<const bf16x8*>(smem + paddr);
      #pragma unroll
      for (int ntp = 0; ntp < 4; ++ntp) {
        int vrow = ntp * 16 + (l & 15);                 // dh index
        int vcb = 2 * (ch * 64 + ks * 32 + (l >> 4) * 8);  // token index bytes
        int vaddr = 32768 + vrow * 512 + (vcb ^ ((vrow & 7) << 4));
        bf16x8 vf = *reinterpret_cast<const bf16x8*>(smem + vaddr);
        oacc[ntp] = __builtin_amdgcn_mfma_f32_16x16x32_bf16(pf, vf, oacc[ntp], 0, 0, 0);
      }
    }
  }

  // ---- epilogue: normalize and store ----
  size_t orow = (size_t)bhi * T_TOK + (size_t)u * 128 + m0 + (l >> 4) * 4;
  float* ob = out + orow * 64 + (l & 15);
  #pragma unroll
  for (int j = 0; j < 4; ++j) {
    #pragma unroll
    for (int ntp = 0; ntp < 4; ++ntp) {
      ob[(size_t)j * 64 + ntp * 16] = oacc[ntp][j] * inv[j];
    }
  }
}

extern "C" void kernel_launch(void* const* d_in, const int* in_sizes, int n_in,
                              void* d_out, int out_size, void* d_ws, size_t ws_size,
                              hipStream_t stream) {
  const float* q = (const float*)d_in[0];
  const float* k = (const float*)d_in[1];
  const float* v = (const float*)d_in[2];
  const float* W = (const float*)d_in[3];
  float* out = (float*)d_out;

  float* x = (float*)d_ws;                                  // 32*64*128 f32 = 1 MB
  int* ridx = (int*)((char*)d_ws + (1 << 20));              // 2048 ints
  float* rval = (float*)((char*)d_ws + (1 << 20) + 8192);   // 2048 floats

  hipLaunchKernelGGL(k1_sums, dim3(2048), dim3(128), 0, stream, q, k, x);
  hipLaunchKernelGGL(k2_sort, dim3(32), dim3(64), 0, stream, x, W, ridx, rval);
  hipLaunchKernelGGL(k3_attn, dim3(2048), dim3(512), 0, stream, q, k, v, ridx, rval, out);
}

// Round 2
// 111.513 us; speedup vs baseline: 1.0379x; 1.0379x over previous
//
#include <hip/hip_runtime.h>

// SinkhornAttention: b=4,h=8,t=8192,dh=64, BUCKETS=64, bucket size 128.
// k1: bucket sums -> x[bh][64][128]
// k2: R=softmax(relu(x@W)); top-1 -> (vu, ru) per (bh,u)
// k3: per-bucket attention, 32x32 swapped-MFMA form (S^T = mfma(K,Q)):
//     softmax lane-local, P->A-frag via cvt_pk + permlane32_swap (no LDS roundtrip).

#define T_TOK 8192
// 512^-0.5 * log2(e): fold into Q so QK^T lands directly in exp2 domain.
#define CQ (0.04419417382415922f * 1.4426950408889634f)

typedef __attribute__((ext_vector_type(4))) float f32x4;
typedef __attribute__((ext_vector_type(16))) float f32x16;
typedef __attribute__((ext_vector_type(8))) short bf16x8;

__device__ __forceinline__ unsigned short f2bf(float f) {
  union { float f; unsigned u; } v; v.f = f;
  unsigned r = v.u + 0x7FFFu + ((v.u >> 16) & 1u);  // RNE
  return (unsigned short)(r >> 16);
}
__device__ __forceinline__ unsigned pack2(float a, float b) {
  return (unsigned)f2bf(a) | ((unsigned)f2bf(b) << 16);
}

// ---------------- Kernel 1: bucket summaries ----------------
__global__ __launch_bounds__(128) void k1_sums(const float* __restrict__ q,
                                               const float* __restrict__ k,
                                               float* __restrict__ x) {
  int G = blockIdx.x;
  int bhi = G >> 6, u = G & 63;
  int tid = threadIdx.x;
  const float* src = (tid < 64) ? q : k;
  int d = tid & 63;
  const float* p = src + ((size_t)bhi * T_TOK + (size_t)u * 128) * 64 + d;
  float s = 0.f;
  #pragma unroll 8
  for (int t = 0; t < 128; ++t) s += p[(size_t)t * 64];
  x[(size_t)G * 128 + tid] = s;
}

// ---------------- Kernel 2: SortNet top-1 ----------------
__global__ __launch_bounds__(64) void k2_sort(const float* __restrict__ x,
                                              const float* __restrict__ W,
                                              int* __restrict__ ridx,
                                              float* __restrict__ rval) {
  __shared__ float xs[64][132];
  __shared__ float Ws[128][64];
  int bhi = blockIdx.x;
  int u = threadIdx.x;
  int hh = bhi & 7;
  for (int i = u; i < 64 * 128; i += 64) xs[i >> 7][i & 127] = x[(size_t)bhi * 8192 + i];
  for (int i = u; i < 128 * 64; i += 64) Ws[i >> 6][i & 63] = W[(size_t)hh * 8192 + i];
  __syncthreads();

  float acc[64];
  #pragma unroll
  for (int i = 0; i < 64; ++i) acc[i] = 0.f;
  for (int kk = 0; kk < 128; ++kk) {
    float xr = xs[u][kk];
    #pragma unroll
    for (int vv = 0; vv < 64; ++vv) acc[vv] = fmaf(xr, Ws[kk][vv], acc[vv]);
  }
  float best = -1.f; int bidx = 0;
  #pragma unroll
  for (int vv = 0; vv < 64; ++vv) {
    float a = fmaxf(acc[vv], 0.f);
    acc[vv] = a;
    if (a > best) { best = a; bidx = vv; }
  }
  float s = 0.f;
  #pragma unroll
  for (int vv = 0; vv < 64; ++vv) s += __expf(acc[vv] - best);
  ridx[bhi * 64 + u] = bidx;
  rval[bhi * 64 + u] = 1.f / s;
}

// ---------------- Kernel 3: bucketed attention (32x32 swapped) ----------------
// grid 2048, block 256 (4 waves). Wave w owns Q rows [32w,32w+32).
// LDS: [0,32768)      KB: K_cat bf16 [256 tok][64 dh], byte ^ ((tok&7)<<4)
//      [32768,65536)  VT: V^T  bf16 [64 dh][256 tok], byte ^ ((d&31)<<4)
//      [65536,81920)  TS: transpose scratch bf16 [128][64], byte ^ ((t&7)<<4)
__global__ __launch_bounds__(256, 2) void k3_attn(
    const float* __restrict__ q, const float* __restrict__ k,
    const float* __restrict__ v, const int* __restrict__ ridx,
    const float* __restrict__ rval, float* __restrict__ out) {
  __shared__ unsigned char smem[81920];

  int L = blockIdx.x;
  int G = ((L & 7) << 8) | (L >> 3);  // XCD swizzle (2048 % 8 == 0)
  int bhi = G >> 6, u = G & 63;
  int tid = threadIdx.x;
  int l = tid & 63;
  int w = tid >> 6;
  int lhi = l >> 5;       // 0/1 half-wave
  int ln = l & 31;

  int vu = ridx[G];
  float ru = rval[G];

  const float* kb = k + (size_t)bhi * (T_TOK * 64);
  const float* vb = v + (size_t)bhi * (T_TOK * 64);

  // ---- stage K_cat (rows 0..127 = bucket vu, 128..255 = bucket u) ----
  #pragma unroll
  for (int it = 0; it < 16; ++it) {
    int ci = tid + it * 256;          // 0..4095 8-byte chunks
    int row = ci >> 4, c4 = ci & 15;  // 16 chunks (of 4 f32) per row
    int srow = (row < 128) ? (vu * 128 + row) : (u * 128 + row - 128);
    float4 val = *reinterpret_cast<const float4*>(kb + (size_t)srow * 64 + c4 * 4);
    int addr = row * 128 + ((c4 * 8) ^ ((row & 7) << 4));
    *reinterpret_cast<uint2*>(smem + addr) = make_uint2(pack2(val.x, val.y), pack2(val.z, val.w));
  }

  // ---- Q B-frags: Q[qr][dh], pre-scaled by CQ, bf16 ----
  const float* qrow = q + ((size_t)bhi * T_TOK + (size_t)u * 128 + w * 32 + ln) * 64;
  bf16x8 qf[4];
  #pragma unroll
  for (int sl = 0; sl < 4; ++sl) {
    float4 a = *reinterpret_cast<const float4*>(qrow + sl * 16 + lhi * 8);
    float4 b = *reinterpret_cast<const float4*>(qrow + sl * 16 + lhi * 8 + 4);
    bf16x8 f;
    f[0] = (short)f2bf(a.x * CQ); f[1] = (short)f2bf(a.y * CQ);
    f[2] = (short)f2bf(a.z * CQ); f[3] = (short)f2bf(a.w * CQ);
    f[4] = (short)f2bf(b.x * CQ); f[5] = (short)f2bf(b.y * CQ);
    f[6] = (short)f2bf(b.z * CQ); f[7] = (short)f2bf(b.w * CQ);
    qf[sl] = f;
  }

  // ---- V transpose rounds: bucket -> TS (row-major) -> VT (transposed) ----
  #pragma unroll
  for (int h = 0; h < 2; ++h) {
    int sb = h ? u : vu;
    {
      int t = tid >> 1;
      const float* src = vb + (size_t)(sb * 128 + t) * 64 + (tid & 1) * 32;
      #pragma unroll
      for (int j = 0; j < 8; ++j) {
        int c = (tid & 1) * 8 + j;
        float4 val = *reinterpret_cast<const float4*>(src + j * 4);
        int addr = 65536 + t * 128 + ((c * 8) ^ ((t & 7) << 4));
        *reinterpret_cast<uint2*>(smem + addr) = make_uint2(pack2(val.x, val.y), pack2(val.z, val.w));
      }
    }
    __syncthreads();
    {
      int d = tid & 63, tq = tid >> 6;
      #pragma unroll
      for (int jj = 0; jj < 16; ++jj) {
        int p = (jj + (d & 15)) & 15;   // stagger for bank spread
        int t0 = tq * 32 + 2 * p;
        unsigned lo = *reinterpret_cast<const unsigned short*>(
            smem + 65536 + t0 * 128 + ((2 * d) ^ ((t0 & 7) << 4)));
        unsigned hi2 = *reinterpret_cast<const unsigned short*>(
            smem + 65536 + (t0 + 1) * 128 + ((2 * d) ^ (((t0 + 1) & 7) << 4)));
        int tt = h * 128 + t0;
        int addr = 32768 + d * 512 + ((2 * tt) ^ ((d & 31) << 4));
        *reinterpret_cast<unsigned*>(smem + addr) = lo | (hi2 << 16);
      }
    }
    __syncthreads();
  }

  // ---- QK^T: S^T tiles (tok x qrow), tiles 0-3 = vu chunk, 4-7 = own ----
  f32x16 s[8];
  #pragma unroll
  for (int t8 = 0; t8 < 8; ++t8) {
    f32x16 acc;
    #pragma unroll
    for (int r = 0; r < 16; ++r) acc[r] = 0.f;
    int tokr = t8 * 32 + ln;
    #pragma unroll
    for (int sl = 0; sl < 4; ++sl) {
      int addr = tokr * 128 + ((sl * 32 + lhi * 16) ^ ((tokr & 7) << 4));
      bf16x8 af = *reinterpret_cast<const bf16x8*>(smem + addr);
      acc = __builtin_amdgcn_mfma_f32_32x32x16_bf16(af, qf[sl], acc, 0, 0, 0);
    }
    s[t8] = acc;
  }

  // ---- softmax: lane-local (each lane owns qrow = ln, half the tokens) ----
  float m03 = -3.0e38f, m47 = -3.0e38f;
  #pragma unroll
  for (int t8 = 0; t8 < 4; ++t8) {
    #pragma unroll
    for (int r = 0; r < 16; ++r) m03 = fmaxf(m03, s[t8][r]);
  }
  #pragma unroll
  for (int t8 = 4; t8 < 8; ++t8) {
    #pragma unroll
    for (int r = 0; r < 16; ++r) m47 = fmaxf(m47, s[t8][r]);
  }
  m03 = fmaxf(m03, __shfl_xor(m03, 32, 64));
  m47 = fmaxf(m47, __shfl_xor(m47, 32, 64));
  float m = fmaxf(ru * m03, m47);  // vu-chunk logits are ru * s (ru >= 0)

  float ssum = 0.f;
  #pragma unroll
  for (int t8 = 0; t8 < 8; ++t8) {
    #pragma unroll
    for (int r = 0; r < 16; ++r) {
      float arg = (t8 < 4) ? fmaf(s[t8][r], ru, -m) : (s[t8][r] - m);
      float e;
      asm("v_exp_f32 %0, %1\n\ts_nop 0" : "=v"(e) : "v"(arg));
      s[t8][r] = e;
      ssum += e;
    }
  }
  ssum += __shfl_xor(ssum, 32, 64);
  float inv = 1.f / ssum;

  // ---- PV: per tile, pack P to bf16 A-frags in-register, mfma with V^T ----
  f32x16 o0, o1;
  #pragma unroll
  for (int r = 0; r < 16; ++r) { o0[r] = 0.f; o1[r] = 0.f; }

  #pragma unroll
  for (int t8 = 0; t8 < 8; ++t8) {
    float mult = (t8 < 4) ? (ru * inv) : inv;  // V_cat first half scaled by ru
    float pv[16];
    #pragma unroll
    for (int r = 0; r < 16; ++r) pv[r] = s[t8][r] * mult;
    #pragma unroll
    for (int ks = 0; ks < 2; ++ks) {
      int r0 = 8 * ks;
      unsigned aA, bA, aB, bB;
      asm("v_cvt_pk_bf16_f32 %0, %1, %2" : "=v"(aA) : "v"(pv[r0 + 0]), "v"(pv[r0 + 1]));
      asm("v_cvt_pk_bf16_f32 %0, %1, %2" : "=v"(bA) : "v"(pv[r0 + 2]), "v"(pv[r0 + 3]));
      asm("v_cvt_pk_bf16_f32 %0, %1, %2" : "=v"(aB) : "v"(pv[r0 + 4]), "v"(pv[r0 + 5]));
      asm("v_cvt_pk_bf16_f32 %0, %1, %2" : "=v"(bB) : "v"(pv[r0 + 6]), "v"(pv[r0 + 7]));
      asm("s_nop 1\n\tv_permlane32_swap_b32 %0, %1\n\ts_nop 1" : "+v"(aA), "+v"(aB));
      asm("s_nop 1\n\tv_permlane32_swap_b32 %0, %1\n\ts_nop 1" : "+v"(bA), "+v"(bB));
      union { unsigned uu[4]; bf16x8 f; } pf;
      pf.uu[0] = aA; pf.uu[1] = bA; pf.uu[2] = aB; pf.uu[3] = bB;

      int tokb = t8 * 32 + ks * 16 + lhi * 8;
      {
        int d = ln;
        int addr = 32768 + d * 512 + ((2 * tokb) ^ ((d & 31) << 4));
        bf16x8 vf = *reinterpret_cast<const bf16x8*>(smem + addr);
        o0 = __builtin_amdgcn_mfma_f32_32x32x16_bf16(pf.f, vf, o0, 0, 0, 0);
      }
      {
        int d = 32 + ln;
        int addr = 32768 + d * 512 + ((2 * tokb) ^ ((d & 31) << 4));
        bf16x8 vf = *reinterpret_cast<const bf16x8*>(smem + addr);
        o1 = __builtin_amdgcn_mfma_f32_32x32x16_bf16(pf.f, vf, o1, 0, 0, 0);
      }
    }
  }

  // ---- store O (normalization already folded into P) ----
  float* ob = out + ((size_t)bhi * T_TOK + (size_t)u * 128 + w * 32) * 64;
  #pragma unroll
  for (int r = 0; r < 16; ++r) {
    int row = (r & 3) + 8 * (r >> 2) + 4 * lhi;
    ob[(size_t)row * 64 + ln] = o0[r];
    ob[(size_t)row * 64 + 32 + ln] = o1[r];
  }
}

extern "C" void kernel_launch(void* const* d_in, const int* in_sizes, int n_in,
                              void* d_out, int out_size, void* d_ws, size_t ws_size,
                              hipStream_t stream) {
  const float* q = (const float*)d_in[0];
  const float* k = (const float*)d_in[1];
  const float* v = (const float*)d_in[2];
  const float* W = (const float*)d_in[3];
  float* out = (float*)d_out;

  float* x = (float*)d_ws;
  int* ridx = (int*)((char*)d_ws + (1 << 20));
  float* rval = (float*)((char*)d_ws + (1 << 20) + 8192);

  hipLaunchKernelGGL(k1_sums, dim3(2048), dim3(128), 0, stream, q, k, x);
  hipLaunchKernelGGL(k2_sort, dim3(32), dim3(64), 0, stream, x, W, ridx, rval);
  hipLaunchKernelGGL(k3_attn, dim3(2048), dim3(256), 0, stream, q, k, v, ridx, rval, out);
}